// Round 9
// baseline (487.564 us; speedup 1.0000x reference)
//
#include <hip/hip_runtime.h>
#include <hip/hip_bf16.h>
#include <math.h>

#define NEG_SLOPE 0.2f
#define BK_BITS 9
#define BK (1 << BK_BITS)   // 512 dst per bucket -> NB = 196 buckets
#define SBITS 17            // bits for src id (N=100000 < 2^17)
#define SMASK ((1 << SBITS) - 1)

__device__ __forceinline__ float lrelu(float x) { return x > 0.f ? x : NEG_SLOPE * x; }

// ==================== bucketed edge partition ====================
__global__ void zero_buckets(int* __restrict__ bcnt, int NB) {
    int i = blockIdx.x * blockDim.x + threadIdx.x;
    if (i < NB) bcnt[i] = 0;
}

__global__ void bucket_hist(const int* __restrict__ dst, int* __restrict__ bcnt,
                            int E, int NB) {
    __shared__ int h[256];
    int t = threadIdx.x;
    h[t] = 0;
    __syncthreads();
    int E4 = E >> 2;
    const int4* dst4 = (const int4*)dst;
    for (int i = blockIdx.x * blockDim.x + t; i < E4; i += gridDim.x * blockDim.x) {
        int4 v = dst4[i];
        atomicAdd(&h[v.x >> BK_BITS], 1);
        atomicAdd(&h[v.y >> BK_BITS], 1);
        atomicAdd(&h[v.z >> BK_BITS], 1);
        atomicAdd(&h[v.w >> BK_BITS], 1);
    }
    for (int e = (E4 << 2) + blockIdx.x * blockDim.x + t; e < E;
         e += gridDim.x * blockDim.x)
        atomicAdd(&h[dst[e] >> BK_BITS], 1);
    __syncthreads();
    if (t < NB && h[t]) atomicAdd(&bcnt[t], h[t]);
}

// single block, 256 threads; NB <= 256. boff = exclusive scan; bcur = boff copy.
__global__ void bucket_scan(const int* __restrict__ bcnt, int* __restrict__ boff,
                            int* __restrict__ bcur, int NB) {
    __shared__ int sc[256];
    int t = threadIdx.x;
    sc[t] = (t < NB) ? bcnt[t] : 0;
    __syncthreads();
    for (int off = 1; off < 256; off <<= 1) {
        int u = (t >= off) ? sc[t - off] : 0;
        __syncthreads();
        sc[t] += u;
        __syncthreads();
    }
    int excl = (t == 0) ? 0 : sc[t - 1];
    if (t <= NB) boff[t] = excl;
    if (t < NB) bcur[t] = excl;
}

// block-aggregated scatter: int4 loads; LDS hist -> one global atomic per
// (block,bucket) -> packed-pair writes via LDS cursors. 4096 edges per block.
__global__ __launch_bounds__(256) void bucket_scatter(const int* __restrict__ src,
                                                      const int* __restrict__ dst,
                                                      int* __restrict__ bcur,
                                                      int* __restrict__ pairs, int E) {
    __shared__ int hist[256];
    int t = threadIdx.x;
    hist[t] = 0;
    __syncthreads();
    int E4 = E >> 2;
    const int4* src4 = (const int4*)src;
    const int4* dst4 = (const int4*)dst;
    int base4 = blockIdx.x * 1024;
    int4 d4[4], s4[4];
    bool val[4];
#pragma unroll
    for (int k = 0; k < 4; k++) {
        int i4 = base4 + k * 256 + t;
        val[k] = (i4 < E4);
        if (val[k]) {
            d4[k] = dst4[i4];
            s4[k] = src4[i4];
            atomicAdd(&hist[d4[k].x >> BK_BITS], 1);
            atomicAdd(&hist[d4[k].y >> BK_BITS], 1);
            atomicAdd(&hist[d4[k].z >> BK_BITS], 1);
            atomicAdd(&hist[d4[k].w >> BK_BITS], 1);
        }
    }
    // scalar tail (E not multiple of 4), handled by last block
    int dt = -1, st = 0;
    if (blockIdx.x == gridDim.x - 1) {
        int e = (E4 << 2) + t;
        if (e < E) {
            dt = dst[e];
            st = src[e];
            atomicAdd(&hist[dt >> BK_BITS], 1);
        }
    }
    __syncthreads();
    int cnt = hist[t];
    __syncthreads();
    if (cnt > 0) hist[t] = atomicAdd(&bcur[t], cnt);  // reserve run for this bucket
    __syncthreads();
#pragma unroll
    for (int k = 0; k < 4; k++) {
        if (val[k]) {
            int pos;
            pos = atomicAdd(&hist[d4[k].x >> BK_BITS], 1);
            pairs[pos] = ((d4[k].x & (BK - 1)) << SBITS) | s4[k].x;
            pos = atomicAdd(&hist[d4[k].y >> BK_BITS], 1);
            pairs[pos] = ((d4[k].y & (BK - 1)) << SBITS) | s4[k].y;
            pos = atomicAdd(&hist[d4[k].z >> BK_BITS], 1);
            pairs[pos] = ((d4[k].z & (BK - 1)) << SBITS) | s4[k].z;
            pos = atomicAdd(&hist[d4[k].w >> BK_BITS], 1);
            pairs[pos] = ((d4[k].w & (BK - 1)) << SBITS) | s4[k].w;
        }
    }
    if (dt >= 0) {
        int pos = atomicAdd(&hist[dt >> BK_BITS], 1);
        pairs[pos] = ((dt & (BK - 1)) << SBITS) | st;
    }
}

// ==================== layer 1: one block per bucket, LDS accumulators ============
// Per-edge weight w = exp(lrelu(xs.x*P[h]+xs.y*Q[h]+ald[h])); accumulate
// Sw/S0/S1 per (head,dst) in LDS via ds_add_f32. Self-loop added analytically in
// the epilogue, which also fuses b1+elu+W2+att2 -> h2[d], al2d[d].
__global__ __launch_bounds__(1024) void agg1_bucket(
        const int* __restrict__ pairs, const int* __restrict__ boff,
        const float2* __restrict__ x2,
        const float* __restrict__ W1, const float* __restrict__ asrc,
        const float* __restrict__ adst, const float* __restrict__ b1,
        const float* __restrict__ W2, const float* __restrict__ as2,
        const float* __restrict__ ad2,
        float2* __restrict__ h2, float* __restrict__ al2d, int N) {
    __shared__ float sW[64], sB[32], sW2[64], sP[4], sQ[4], sPd[4], sQd[4], sA2[4];
    __shared__ float ald_s[4][BK];   // 8 KB
    __shared__ float acc[12][BK];    // 24 KB: [h]=Sw, [4+h]=S0, [8+h]=S1
    int t = threadIdx.x;
    int b = blockIdx.x;
    int dbase = b << BK_BITS;
    int ndst = min(BK, N - dbase);

    if (t < 64) { sW[t] = W1[t]; sW2[t] = W2[t]; }
    if (t < 32) sB[t] = b1[t];
    if (t < 2) { sA2[t] = as2[t]; sA2[2 + t] = ad2[t]; }
    if (t < 4) {
        float P = 0.f, Q = 0.f, Pd = 0.f, Qd = 0.f;
#pragma unroll
        for (int k = 0; k < 8; k++) {
            int c = t * 8 + k;
            float a = asrc[c], ad_ = adst[c];
            float w0 = W1[c], w1 = W1[32 + c];
            P += w0 * a; Q += w1 * a;
            Pd += w0 * ad_; Qd += w1 * ad_;
        }
        sP[t] = P; sQ[t] = Q; sPd[t] = Pd; sQd[t] = Qd;
    }
    for (int i = t; i < 12 * BK; i += 1024) ((float*)acc)[i] = 0.f;
    __syncthreads();

    // per-dst ald[h]
    for (int i = t; i < ndst; i += 1024) {
        float2 xd = x2[dbase + i];
#pragma unroll
        for (int h = 0; h < 4; h++)
            ald_s[h][i] = xd.x * sPd[h] + xd.y * sQd[h];
    }
    __syncthreads();

    // stream this bucket's pairs
    int lo = boff[b], hi = boff[b + 1];
    float P0 = sP[0], P1 = sP[1], P2 = sP[2], P3 = sP[3];
    float Q0 = sQ[0], Q1 = sQ[1], Q2 = sQ[2], Q3 = sQ[3];
    for (int i = lo + t; i < hi; i += 1024) {
        int p = pairs[i];
        int dloc = p >> SBITS;
        int s = p & SMASK;
        float2 xs = x2[s];
        float w0 = __expf(fminf(lrelu(fmaf(xs.x, P0, fmaf(xs.y, Q0, ald_s[0][dloc]))), 80.f));
        float w1 = __expf(fminf(lrelu(fmaf(xs.x, P1, fmaf(xs.y, Q1, ald_s[1][dloc]))), 80.f));
        float w2 = __expf(fminf(lrelu(fmaf(xs.x, P2, fmaf(xs.y, Q2, ald_s[2][dloc]))), 80.f));
        float w3 = __expf(fminf(lrelu(fmaf(xs.x, P3, fmaf(xs.y, Q3, ald_s[3][dloc]))), 80.f));
        atomicAdd(&acc[0][dloc], w0);
        atomicAdd(&acc[1][dloc], w1);
        atomicAdd(&acc[2][dloc], w2);
        atomicAdd(&acc[3][dloc], w3);
        atomicAdd(&acc[4][dloc], w0 * xs.x);
        atomicAdd(&acc[5][dloc], w1 * xs.x);
        atomicAdd(&acc[6][dloc], w2 * xs.x);
        atomicAdd(&acc[7][dloc], w3 * xs.x);
        atomicAdd(&acc[8][dloc], w0 * xs.y);
        atomicAdd(&acc[9][dloc], w1 * xs.y);
        atomicAdd(&acc[10][dloc], w2 * xs.y);
        atomicAdd(&acc[11][dloc], w3 * xs.y);
    }
    __syncthreads();

    // epilogue: one dst per thread; add self-loop analytically; fuse node2
    for (int i = t; i < ndst; i += 1024) {
        int d = dbase + i;
        float2 xd = x2[d];
        float Sw[4], S0[4], S1[4];
#pragma unroll
        for (int h = 0; h < 4; h++) {
            float als = xd.x * sP[h] + xd.y * sQ[h];
            float e = lrelu(als + ald_s[h][i]);
            float w = __expf(fminf(e, 80.f));
            Sw[h] = acc[h][i] + w;
            S0[h] = acc[4 + h][i] + w * xd.x;
            S1[h] = acc[8 + h][i] + w * xd.y;
        }
        float r[4];
#pragma unroll
        for (int h = 0; h < 4; h++) r[h] = 1.f / (Sw[h] + 1e-16f);
        float h20 = 0.f, h21 = 0.f;
#pragma unroll
        for (int c = 0; c < 32; c++) {
            int h = c >> 3;
            float outc = (sW[c] * S0[h] + sW[32 + c] * S1[h]) * r[h];
            float v2 = outc + sB[c];
            v2 = v2 > 0.f ? v2 : __expf(v2) - 1.f;  // elu
            h20 = fmaf(v2, sW2[2 * c], h20);
            h21 = fmaf(v2, sW2[2 * c + 1], h21);
        }
        h2[d] = make_float2(h20, h21);
        al2d[d] = h20 * sA2[2] + h21 * sA2[3];
    }
}

// ==================== layer 2: one block per bucket, LDS accumulators ============
__global__ __launch_bounds__(1024) void agg2_bucket(
        const int* __restrict__ pairs, const int* __restrict__ boff,
        const float2* __restrict__ h2, const float* __restrict__ al2d,
        const float* __restrict__ as2, const float* __restrict__ b2,
        float2* __restrict__ out, int N) {
    __shared__ float ald_s[BK];     // 2 KB
    __shared__ float acc[3][BK];    // 6 KB: wsum, ax, ay
    int t = threadIdx.x;
    int b = blockIdx.x;
    int dbase = b << BK_BITS;
    int ndst = min(BK, N - dbase);
    float a0 = as2[0], a1 = as2[1];
    float bb0 = b2[0], bb1 = b2[1];

    for (int i = t; i < 3 * BK; i += 1024) ((float*)acc)[i] = 0.f;
    for (int i = t; i < ndst; i += 1024) ald_s[i] = al2d[dbase + i];
    __syncthreads();

    int lo = boff[b], hi = boff[b + 1];
    for (int i = lo + t; i < hi; i += 1024) {
        int p = pairs[i];
        int dloc = p >> SBITS;
        int s = p & SMASK;
        float2 hv = h2[s];
        float e = lrelu(fmaf(hv.x, a0, fmaf(hv.y, a1, ald_s[dloc])));
        float w = __expf(fminf(e, 80.f));
        atomicAdd(&acc[0][dloc], w);
        atomicAdd(&acc[1][dloc], w * hv.x);
        atomicAdd(&acc[2][dloc], w * hv.y);
    }
    __syncthreads();

    for (int i = t; i < ndst; i += 1024) {
        int d = dbase + i;
        float2 hd = h2[d];
        float e = lrelu(fmaf(hd.x, a0, fmaf(hd.y, a1, ald_s[i])));
        float w = __expf(fminf(e, 80.f));   // self-loop
        float wsum = acc[0][i] + w;
        float ax = acc[1][i] + w * hd.x;
        float ay = acc[2][i] + w * hd.y;
        float inv = 1.f / (wsum + 1e-16f);
        out[d] = make_float2(ax * inv + bb0, ay * inv + bb1);
    }
}

extern "C" void kernel_launch(void* const* d_in, const int* in_sizes, int n_in,
                              void* d_out, int out_size, void* d_ws, size_t ws_size,
                              hipStream_t stream) {
    const float* x     = (const float*)d_in[0];
    const int*   eidx  = (const int*)d_in[1];
    const float* W1    = (const float*)d_in[3];
    const float* asrc1 = (const float*)d_in[4];
    const float* adst1 = (const float*)d_in[5];
    const float* b1    = (const float*)d_in[6];
    const float* W2    = (const float*)d_in[7];
    const float* asrc2 = (const float*)d_in[8];
    const float* adst2 = (const float*)d_in[9];
    const float* b2    = (const float*)d_in[10];

    const int N = in_sizes[0] / 2;   // 100000 (< 2^17 for packing)
    const int E = in_sizes[1] / 2;   // 3200000
    const int* src = eidx;
    const int* dst = eidx + E;
    const int NB = (N + BK - 1) >> BK_BITS;   // 196

    // -------- workspace layout --------
    float* w = (float*)d_ws;
    float2* h2   = (float2*)w;                 // 2N floats
    float*  al2d = w + 2 * (size_t)N;          // N
    int* ip     = (int*)(w + 3 * (size_t)N);
    int* bcnt   = ip;                          // NB
    int* boff   = ip + NB;                     // NB+1
    int* bcur   = ip + 2 * NB + 1;             // NB
    int* pairs  = ip + 3 * NB + 2;             // E ints (packed dloc|src)

    const int B = 256;
    int gS = (E + 4095) / 4096;    // scatter blocks (4096 edges each)

    zero_buckets<<<1, B, 0, stream>>>(bcnt, NB);
    bucket_hist<<<1024, B, 0, stream>>>(dst, bcnt, E, NB);
    bucket_scan<<<1, B, 0, stream>>>(bcnt, boff, bcur, NB);
    bucket_scatter<<<gS, B, 0, stream>>>(src, dst, bcur, pairs, E);

    agg1_bucket<<<NB, 1024, 0, stream>>>(pairs, boff, (const float2*)x,
                                         W1, asrc1, adst1, b1, W2, asrc2, adst2,
                                         h2, al2d, N);
    agg2_bucket<<<NB, 1024, 0, stream>>>(pairs, boff, h2, al2d, asrc2, b2,
                                         (float2*)d_out, N);
}

// Round 10
// 215.388 us; speedup vs baseline: 2.2637x; 2.2637x over previous
//
#include <hip/hip_runtime.h>
#include <hip/hip_bf16.h>
#include <math.h>

#define NEG_SLOPE 0.2f
#define BK_BITS 9
#define BK (1 << BK_BITS)     // 512 dst per bucket -> NB = 196 buckets
#define SBITS 17              // bits for src id (N=100000 < 2^17)
#define SMASK ((1 << SBITS) - 1)
#define CAP 20480             // pairs capacity per bucket (mean 16327, +32 sigma)

__device__ __forceinline__ float lrelu(float x) { return x > 0.f ? x : NEG_SLOPE * x; }

// ==================== init bucket cursors ====================
__global__ void init_bcur(int* __restrict__ bcur, int NB) {
    int i = threadIdx.x;
    if (i < NB) bcur[i] = i * CAP;
}

// ==================== LDS-staged bucketed scatter ====================
// 4096 edges/block: count -> LDS scan -> place grouped in LDS -> reserve global
// runs (1 atomic per block,bucket) -> coalesced grouped writes.
__global__ __launch_bounds__(256) void bucket_scatter(const int* __restrict__ src,
                                                      const int* __restrict__ dst,
                                                      int* __restrict__ bcur,
                                                      int* __restrict__ pairs, int E) {
    __shared__ int cnt[256], sc[256], off[256], cur[256], gbase[256];
    __shared__ int lpair[4096];
    __shared__ unsigned char lbkt[4096];
    int t = threadIdx.x;
    cnt[t] = 0;
    __syncthreads();

    int E4 = E >> 2;
    const int4* src4 = (const int4*)src;
    const int4* dst4 = (const int4*)dst;
    int base4 = blockIdx.x * 1024;
    int4 d4[4], s4[4];
    bool val[4];
#pragma unroll
    for (int k = 0; k < 4; k++) {
        int i4 = base4 + k * 256 + t;
        val[k] = (i4 < E4);
        if (val[k]) {
            d4[k] = dst4[i4];
            s4[k] = src4[i4];
            atomicAdd(&cnt[d4[k].x >> BK_BITS], 1);
            atomicAdd(&cnt[d4[k].y >> BK_BITS], 1);
            atomicAdd(&cnt[d4[k].z >> BK_BITS], 1);
            atomicAdd(&cnt[d4[k].w >> BK_BITS], 1);
        }
    }
    // scalar tail (last block)
    int dt = -1, st = 0;
    if (blockIdx.x == gridDim.x - 1) {
        int e = (E4 << 2) + t;
        if (e < E) { dt = dst[e]; st = src[e]; atomicAdd(&cnt[dt >> BK_BITS], 1); }
    }
    __syncthreads();

    sc[t] = cnt[t];
    __syncthreads();
    for (int o = 1; o < 256; o <<= 1) {
        int u = (t >= o) ? sc[t - o] : 0;
        __syncthreads();
        sc[t] += u;
        __syncthreads();
    }
    int excl = (t == 0) ? 0 : sc[t - 1];
    off[t] = excl;
    cur[t] = excl;
    if (cnt[t] > 0) gbase[t] = atomicAdd(&bcur[t], cnt[t]);
    __syncthreads();
    int total = sc[255];

    // place grouped into LDS
#pragma unroll
    for (int k = 0; k < 4; k++) {
        if (val[k]) {
            int b, slot;
            b = d4[k].x >> BK_BITS; slot = atomicAdd(&cur[b], 1);
            lpair[slot] = ((d4[k].x & (BK - 1)) << SBITS) | s4[k].x; lbkt[slot] = (unsigned char)b;
            b = d4[k].y >> BK_BITS; slot = atomicAdd(&cur[b], 1);
            lpair[slot] = ((d4[k].y & (BK - 1)) << SBITS) | s4[k].y; lbkt[slot] = (unsigned char)b;
            b = d4[k].z >> BK_BITS; slot = atomicAdd(&cur[b], 1);
            lpair[slot] = ((d4[k].z & (BK - 1)) << SBITS) | s4[k].z; lbkt[slot] = (unsigned char)b;
            b = d4[k].w >> BK_BITS; slot = atomicAdd(&cur[b], 1);
            lpair[slot] = ((d4[k].w & (BK - 1)) << SBITS) | s4[k].w; lbkt[slot] = (unsigned char)b;
        }
    }
    if (dt >= 0) {
        int b = dt >> BK_BITS;
        int slot = atomicAdd(&cur[b], 1);
        lpair[slot] = ((dt & (BK - 1)) << SBITS) | st; lbkt[slot] = (unsigned char)b;
    }
    __syncthreads();

    // grouped coalesced-ish writes
    for (int i = t; i < total; i += 256) {
        int b = lbkt[i];
        pairs[gbase[b] + (i - off[b])] = lpair[i];
    }
}

// ==================== CSR build: one block (512 thr) per bucket ====================
// row_deg[n] = (local_offset << 16) | deg ; csr region per bucket = b*(CAP+BK)
__global__ __launch_bounds__(512) void csr_build(const int* __restrict__ pairs,
                                                 const int* __restrict__ bcur,
                                                 int* __restrict__ row_deg,
                                                 int* __restrict__ csr_src, int N) {
    int b = blockIdx.x;
    int t = threadIdx.x;
    int lo = b * CAP, hi = bcur[b];
    int dbase = b << BK_BITS;
    int ndst = min(BK, N - dbase);
    int base2 = b * (CAP + BK);
    __shared__ int cnt[BK];
    __shared__ int sc[256];
    __shared__ int cur[BK];
    if (t < BK) cnt[t] = 0;
    __syncthreads();
    for (int i = lo + t; i < hi; i += blockDim.x) atomicAdd(&cnt[pairs[i] >> SBITS], 1);
    __syncthreads();
    int v0 = 0, v1 = 0;
    if (t < 256) {
        int i0 = 2 * t, i1 = 2 * t + 1;
        v0 = cnt[i0] + (i0 < ndst ? 1 : 0);  // +1 self-loop
        v1 = cnt[i1] + (i1 < ndst ? 1 : 0);
        sc[t] = v0 + v1;
    }
    __syncthreads();
    for (int o = 1; o < 256; o <<= 1) {
        int u = 0;
        if (t < 256 && t >= o) u = sc[t - o];
        __syncthreads();
        if (t < 256) sc[t] += u;
        __syncthreads();
    }
    if (t < 256) {
        int excl = (t == 0) ? 0 : sc[t - 1];
        int i0 = 2 * t, i1 = 2 * t + 1;
        if (i0 < ndst) {
            row_deg[dbase + i0] = (excl << 16) | v0;
            csr_src[base2 + excl] = dbase + i0;  // self-loop first
            cur[i0] = excl + 1;
        }
        excl += v0;
        if (i1 < ndst) {
            row_deg[dbase + i1] = (excl << 16) | v1;
            csr_src[base2 + excl] = dbase + i1;
            cur[i1] = excl + 1;
        }
    }
    __syncthreads();
    for (int i = lo + t; i < hi; i += blockDim.x) {
        int p = pairs[i];
        int pos = atomicAdd(&cur[p >> SBITS], 1);
        csr_src[base2 + pos] = p & SMASK;
    }
}

// ==================== fused layer1: one dst per LANE (no shuffles) ====================
__global__ __launch_bounds__(256) void agg1_dstlane(
        const int* __restrict__ row_deg, const int* __restrict__ csr_src,
        const float2* __restrict__ x2,
        const float* __restrict__ W1, const float* __restrict__ asrc,
        const float* __restrict__ adst, const float* __restrict__ b1,
        const float* __restrict__ W2, const float* __restrict__ as2,
        const float* __restrict__ ad2,
        float2* __restrict__ h2, float* __restrict__ al2d, int N) {
    __shared__ float sW[64], sB[32], sW2[64], sP[4], sQ[4], sPd[4], sQd[4], sA2[4];
    int t = threadIdx.x;
    if (t < 64) { sW[t] = W1[t]; sW2[t] = W2[t]; }
    if (t < 32) sB[t] = b1[t];
    if (t < 2) { sA2[t] = as2[t]; sA2[2 + t] = ad2[t]; }
    if (t < 4) {
        float P = 0.f, Q = 0.f, Pd = 0.f, Qd = 0.f;
#pragma unroll
        for (int k = 0; k < 8; k++) {
            int c = t * 8 + k;
            float a = asrc[c], ad_ = adst[c];
            float w0 = W1[c], w1 = W1[32 + c];
            P += w0 * a; Q += w1 * a;
            Pd += w0 * ad_; Qd += w1 * ad_;
        }
        sP[t] = P; sQ[t] = Q; sPd[t] = Pd; sQd[t] = Qd;
    }
    __syncthreads();

    int n = blockIdx.x * blockDim.x + t;
    if (n >= N) return;
    int rd = row_deg[n];
    int row = (n >> BK_BITS) * (CAP + BK) + (rd >> 16);
    int deg = rd & 0xFFFF;

    float2 xd = x2[n];
    float P[4], Q[4], ald[4];
#pragma unroll
    for (int h = 0; h < 4; h++) {
        P[h] = sP[h]; Q[h] = sQ[h];
        ald[h] = xd.x * sPd[h] + xd.y * sQd[h];
    }

    float Sw[4] = {0.f, 0.f, 0.f, 0.f};
    float S0[4] = {0.f, 0.f, 0.f, 0.f};
    float S1[4] = {0.f, 0.f, 0.f, 0.f};
    for (int j = 0; j < deg; j++) {
        int s = csr_src[row + j];
        float2 xs = x2[s];
#pragma unroll
        for (int h = 0; h < 4; h++) {
            float e = lrelu(fmaf(xs.x, P[h], fmaf(xs.y, Q[h], ald[h])));
            float w = __expf(fminf(e, 80.f));
            Sw[h] += w;
            S0[h] += w * xs.x;
            S1[h] += w * xs.y;
        }
    }

    float r[4];
#pragma unroll
    for (int h = 0; h < 4; h++) r[h] = 1.f / (Sw[h] + 1e-16f);
    float h20 = 0.f, h21 = 0.f;
#pragma unroll
    for (int c = 0; c < 32; c++) {
        int h = c >> 3;
        float outc = (sW[c] * S0[h] + sW[32 + c] * S1[h]) * r[h];
        float v2 = outc + sB[c];
        v2 = v2 > 0.f ? v2 : __expf(v2) - 1.f;  // elu
        h20 = fmaf(v2, sW2[2 * c], h20);
        h21 = fmaf(v2, sW2[2 * c + 1], h21);
    }
    h2[n] = make_float2(h20, h21);
    al2d[n] = h20 * sA2[2] + h21 * sA2[3];
}

// ==================== layer 2 aggregate: one dst per LANE ====================
__global__ __launch_bounds__(256) void agg2_dstlane(
        const int* __restrict__ row_deg, const int* __restrict__ csr_src,
        const float* __restrict__ al2d, const float2* __restrict__ h2,
        const float* __restrict__ as2, const float* __restrict__ b2,
        float2* __restrict__ out, int N) {
    int n = blockIdx.x * blockDim.x + threadIdx.x;
    if (n >= N) return;
    int rd = row_deg[n];
    int row = (n >> BK_BITS) * (CAP + BK) + (rd >> 16);
    int deg = rd & 0xFFFF;
    float ald = al2d[n];
    float a0 = as2[0], a1 = as2[1];
    float bb0 = b2[0], bb1 = b2[1];

    float wsum = 0.f, ax = 0.f, ay = 0.f;
    for (int j = 0; j < deg; j++) {
        int s = csr_src[row + j];
        float2 hv = h2[s];
        float e = lrelu(fmaf(hv.x, a0, fmaf(hv.y, a1, ald)));
        float w = __expf(fminf(e, 80.f));
        wsum += w;
        ax = fmaf(w, hv.x, ax);
        ay = fmaf(w, hv.y, ay);
    }
    float inv = 1.f / (wsum + 1e-16f);
    out[n] = make_float2(ax * inv + bb0, ay * inv + bb1);
}

extern "C" void kernel_launch(void* const* d_in, const int* in_sizes, int n_in,
                              void* d_out, int out_size, void* d_ws, size_t ws_size,
                              hipStream_t stream) {
    const float* x     = (const float*)d_in[0];
    const int*   eidx  = (const int*)d_in[1];
    const float* W1    = (const float*)d_in[3];
    const float* asrc1 = (const float*)d_in[4];
    const float* adst1 = (const float*)d_in[5];
    const float* b1    = (const float*)d_in[6];
    const float* W2    = (const float*)d_in[7];
    const float* asrc2 = (const float*)d_in[8];
    const float* adst2 = (const float*)d_in[9];
    const float* b2    = (const float*)d_in[10];

    const int N = in_sizes[0] / 2;   // 100000 (< 2^17 for packing)
    const int E = in_sizes[1] / 2;   // 3200000
    const int* src = eidx;
    const int* dst = eidx + E;
    const int NB = (N + BK - 1) >> BK_BITS;   // 196

    // -------- workspace layout --------
    float* w = (float*)d_ws;
    float2* h2    = (float2*)w;                 // 2N floats
    float*  al2d  = w + 2 * (size_t)N;          // N
    int* ip       = (int*)(w + 3 * (size_t)N);
    int* row_deg  = ip;                         // N
    int* bcur     = ip + (size_t)N;             // NB
    int* pairs    = ip + (size_t)N + NB;        // NB*CAP
    int* csr_src  = pairs + (size_t)NB * CAP;   // NB*(CAP+BK)

    const int B = 256;
    int gL = (N + B - 1) / B;
    int E4 = E >> 2;
    int gS = (E4 + 1023) / 1024;    // 4096 edges per block

    init_bcur<<<1, B, 0, stream>>>(bcur, NB);
    bucket_scatter<<<gS, B, 0, stream>>>(src, dst, bcur, pairs, E);
    csr_build<<<NB, 512, 0, stream>>>(pairs, bcur, row_deg, csr_src, N);

    agg1_dstlane<<<gL, B, 0, stream>>>(row_deg, csr_src, (const float2*)x,
                                       W1, asrc1, adst1, b1, W2, asrc2, adst2,
                                       h2, al2d, N);
    agg2_dstlane<<<gL, B, 0, stream>>>(row_deg, csr_src, al2d, h2, asrc2, b2,
                                       (float2*)d_out, N);
}

// Round 11
// 190.679 us; speedup vs baseline: 2.5570x; 1.1296x over previous
//
#include <hip/hip_runtime.h>
#include <hip/hip_bf16.h>
#include <math.h>

#define NEG_SLOPE 0.2f
#define BK_BITS 9
#define BK (1 << BK_BITS)     // 512 dst per bucket -> NB = 196 buckets
#define SBITS 17              // bits for src id (N=100000 < 2^17)
#define SMASK ((1 << SBITS) - 1)
#define CAP 20480             // pairs capacity per bucket (mean 16327, +32 sigma)
#define RSTRIDE (CAP + 4 * BK)  // csr region per bucket (rows padded to x4)

__device__ __forceinline__ float lrelu(float x) { return x > 0.f ? x : NEG_SLOPE * x; }

// ==================== init bucket cursors ====================
__global__ void init_bcur(int* __restrict__ bcur, int NB) {
    int i = threadIdx.x;
    if (i < NB) bcur[i] = i * CAP;
}

// ==================== LDS-staged bucketed scatter ====================
__global__ __launch_bounds__(256) void bucket_scatter(const int* __restrict__ src,
                                                      const int* __restrict__ dst,
                                                      int* __restrict__ bcur,
                                                      int* __restrict__ pairs, int E) {
    __shared__ int cnt[256], sc[256], off[256], cur[256], gbase[256];
    __shared__ int lpair[4096];
    __shared__ unsigned char lbkt[4096];
    int t = threadIdx.x;
    cnt[t] = 0;
    __syncthreads();

    int E4 = E >> 2;
    const int4* src4 = (const int4*)src;
    const int4* dst4 = (const int4*)dst;
    int base4 = blockIdx.x * 1024;
    int4 d4[4], s4[4];
    bool val[4];
#pragma unroll
    for (int k = 0; k < 4; k++) {
        int i4 = base4 + k * 256 + t;
        val[k] = (i4 < E4);
        if (val[k]) {
            d4[k] = dst4[i4];
            s4[k] = src4[i4];
            atomicAdd(&cnt[d4[k].x >> BK_BITS], 1);
            atomicAdd(&cnt[d4[k].y >> BK_BITS], 1);
            atomicAdd(&cnt[d4[k].z >> BK_BITS], 1);
            atomicAdd(&cnt[d4[k].w >> BK_BITS], 1);
        }
    }
    int dt = -1, st = 0;
    if (blockIdx.x == gridDim.x - 1) {
        int e = (E4 << 2) + t;
        if (e < E) { dt = dst[e]; st = src[e]; atomicAdd(&cnt[dt >> BK_BITS], 1); }
    }
    __syncthreads();

    sc[t] = cnt[t];
    __syncthreads();
    for (int o = 1; o < 256; o <<= 1) {
        int u = (t >= o) ? sc[t - o] : 0;
        __syncthreads();
        sc[t] += u;
        __syncthreads();
    }
    int excl = (t == 0) ? 0 : sc[t - 1];
    off[t] = excl;
    cur[t] = excl;
    if (cnt[t] > 0) gbase[t] = atomicAdd(&bcur[t], cnt[t]);
    __syncthreads();
    int total = sc[255];

#pragma unroll
    for (int k = 0; k < 4; k++) {
        if (val[k]) {
            int b, slot;
            b = d4[k].x >> BK_BITS; slot = atomicAdd(&cur[b], 1);
            lpair[slot] = ((d4[k].x & (BK - 1)) << SBITS) | s4[k].x; lbkt[slot] = (unsigned char)b;
            b = d4[k].y >> BK_BITS; slot = atomicAdd(&cur[b], 1);
            lpair[slot] = ((d4[k].y & (BK - 1)) << SBITS) | s4[k].y; lbkt[slot] = (unsigned char)b;
            b = d4[k].z >> BK_BITS; slot = atomicAdd(&cur[b], 1);
            lpair[slot] = ((d4[k].z & (BK - 1)) << SBITS) | s4[k].z; lbkt[slot] = (unsigned char)b;
            b = d4[k].w >> BK_BITS; slot = atomicAdd(&cur[b], 1);
            lpair[slot] = ((d4[k].w & (BK - 1)) << SBITS) | s4[k].w; lbkt[slot] = (unsigned char)b;
        }
    }
    if (dt >= 0) {
        int b = dt >> BK_BITS;
        int slot = atomicAdd(&cur[b], 1);
        lpair[slot] = ((dt & (BK - 1)) << SBITS) | st; lbkt[slot] = (unsigned char)b;
    }
    __syncthreads();

    for (int i = t; i < total; i += 256) {
        int b = lbkt[i];
        pairs[gbase[b] + (i - off[b])] = lpair[i];
    }
}

// ==================== CSR build: one block (1024 thr) per bucket ====================
// Rows padded to 4-int alignment; pad slots filled with own dst index (safe for
// speculative int4 loads in agg). row_deg[n] = (local_offset << 16) | deg.
__global__ __launch_bounds__(1024) void csr_build(const int* __restrict__ pairs,
                                                  const int* __restrict__ bcur,
                                                  int* __restrict__ row_deg,
                                                  int* __restrict__ csr_src, int N) {
    int b = blockIdx.x;
    int t = threadIdx.x;
    int lo = b * CAP, hi = bcur[b];
    int dbase = b << BK_BITS;
    int ndst = min(BK, N - dbase);
    int base2 = b * RSTRIDE;
    __shared__ int cnt[BK];
    __shared__ int sc[256];
    __shared__ int cur[BK];
    if (t < BK) cnt[t] = 0;
    __syncthreads();
    for (int i = lo + t; i < hi; i += blockDim.x) atomicAdd(&cnt[pairs[i] >> SBITS], 1);
    __syncthreads();
    int d0 = 0, d1 = 0, a0 = 0, a1 = 0;
    if (t < 256) {
        int i0 = 2 * t, i1 = 2 * t + 1;
        d0 = (i0 < ndst) ? cnt[i0] + 1 : 0;   // +1 self-loop
        d1 = (i1 < ndst) ? cnt[i1] + 1 : 0;
        a0 = (d0 + 3) & ~3;                   // padded size
        a1 = (d1 + 3) & ~3;
        sc[t] = a0 + a1;
    }
    __syncthreads();
    for (int o = 1; o < 256; o <<= 1) {
        int u = 0;
        if (t < 256 && t >= o) u = sc[t - o];
        __syncthreads();
        if (t < 256) sc[t] += u;
        __syncthreads();
    }
    if (t < 256) {
        int excl = (t == 0) ? 0 : sc[t - 1];
        int i0 = 2 * t, i1 = 2 * t + 1;
        if (i0 < ndst) {
            row_deg[dbase + i0] = (excl << 16) | d0;
            csr_src[base2 + excl] = dbase + i0;  // self-loop first
            for (int k = d0; k < a0; k++) csr_src[base2 + excl + k] = dbase + i0;  // pad
            cur[i0] = excl + 1;
        }
        excl += a0;
        if (i1 < ndst) {
            row_deg[dbase + i1] = (excl << 16) | d1;
            csr_src[base2 + excl] = dbase + i1;
            for (int k = d1; k < a1; k++) csr_src[base2 + excl + k] = dbase + i1;
            cur[i1] = excl + 1;
        }
    }
    __syncthreads();
    for (int i = lo + t; i < hi; i += blockDim.x) {
        int p = pairs[i];
        int pos = atomicAdd(&cur[p >> SBITS], 1);
        csr_src[base2 + pos] = p & SMASK;
    }
}

// ==================== fused layer1: one dst per LANE, 4-way ILP ====================
__global__ __launch_bounds__(256) void agg1_dstlane(
        const int* __restrict__ row_deg, const int* __restrict__ csr_src,
        const float2* __restrict__ x2,
        const float* __restrict__ W1, const float* __restrict__ asrc,
        const float* __restrict__ adst, const float* __restrict__ b1,
        const float* __restrict__ W2, const float* __restrict__ as2,
        const float* __restrict__ ad2,
        float2* __restrict__ h2, float* __restrict__ al2d, int N) {
    __shared__ float sW[64], sB[32], sW2[64], sP[4], sQ[4], sPd[4], sQd[4], sA2[4];
    int t = threadIdx.x;
    if (t < 64) { sW[t] = W1[t]; sW2[t] = W2[t]; }
    if (t < 32) sB[t] = b1[t];
    if (t < 2) { sA2[t] = as2[t]; sA2[2 + t] = ad2[t]; }
    if (t < 4) {
        float P = 0.f, Q = 0.f, Pd = 0.f, Qd = 0.f;
#pragma unroll
        for (int k = 0; k < 8; k++) {
            int c = t * 8 + k;
            float a = asrc[c], ad_ = adst[c];
            float w0 = W1[c], w1 = W1[32 + c];
            P += w0 * a; Q += w1 * a;
            Pd += w0 * ad_; Qd += w1 * ad_;
        }
        sP[t] = P; sQ[t] = Q; sPd[t] = Pd; sQd[t] = Qd;
    }
    __syncthreads();

    int n = blockIdx.x * blockDim.x + t;
    if (n >= N) return;
    int rd = row_deg[n];
    int row = (n >> BK_BITS) * RSTRIDE + (rd >> 16);
    int deg = rd & 0xFFFF;

    float2 xd = x2[n];
    float P[4], Q[4], ald[4];
#pragma unroll
    for (int h = 0; h < 4; h++) {
        P[h] = sP[h]; Q[h] = sQ[h];
        ald[h] = xd.x * sPd[h] + xd.y * sQd[h];
    }

    float Sw[4] = {0.f, 0.f, 0.f, 0.f};
    float S0[4] = {0.f, 0.f, 0.f, 0.f};
    float S1[4] = {0.f, 0.f, 0.f, 0.f};
    for (int j = 0; j < deg; j += 4) {
        int4 s4 = *(const int4*)(csr_src + row + j);   // row is 16B-aligned
        float2 xs[4];
        xs[0] = x2[s4.x]; xs[1] = x2[s4.y]; xs[2] = x2[s4.z]; xs[3] = x2[s4.w];
#pragma unroll
        for (int k = 0; k < 4; k++) {
            bool live = (j + k < deg);
#pragma unroll
            for (int h = 0; h < 4; h++) {
                float e = lrelu(fmaf(xs[k].x, P[h], fmaf(xs[k].y, Q[h], ald[h])));
                float w = __expf(fminf(e, 80.f));
                w = live ? w : 0.f;
                Sw[h] += w;
                S0[h] += w * xs[k].x;
                S1[h] += w * xs[k].y;
            }
        }
    }

    float r[4];
#pragma unroll
    for (int h = 0; h < 4; h++) r[h] = 1.f / (Sw[h] + 1e-16f);
    float h20 = 0.f, h21 = 0.f;
#pragma unroll
    for (int c = 0; c < 32; c++) {
        int h = c >> 3;
        float outc = (sW[c] * S0[h] + sW[32 + c] * S1[h]) * r[h];
        float v2 = outc + sB[c];
        v2 = v2 > 0.f ? v2 : __expf(v2) - 1.f;  // elu
        h20 = fmaf(v2, sW2[2 * c], h20);
        h21 = fmaf(v2, sW2[2 * c + 1], h21);
    }
    h2[n] = make_float2(h20, h21);
    al2d[n] = h20 * sA2[2] + h21 * sA2[3];
}

// ==================== layer 2 aggregate: one dst per LANE, 4-way ILP ==============
__global__ __launch_bounds__(256) void agg2_dstlane(
        const int* __restrict__ row_deg, const int* __restrict__ csr_src,
        const float* __restrict__ al2d, const float2* __restrict__ h2,
        const float* __restrict__ as2, const float* __restrict__ b2,
        float2* __restrict__ out, int N) {
    int n = blockIdx.x * blockDim.x + threadIdx.x;
    if (n >= N) return;
    int rd = row_deg[n];
    int row = (n >> BK_BITS) * RSTRIDE + (rd >> 16);
    int deg = rd & 0xFFFF;
    float ald = al2d[n];
    float a0 = as2[0], a1 = as2[1];
    float bb0 = b2[0], bb1 = b2[1];

    float wsum = 0.f, ax = 0.f, ay = 0.f;
    for (int j = 0; j < deg; j += 4) {
        int4 s4 = *(const int4*)(csr_src + row + j);
        float2 hv[4];
        hv[0] = h2[s4.x]; hv[1] = h2[s4.y]; hv[2] = h2[s4.z]; hv[3] = h2[s4.w];
#pragma unroll
        for (int k = 0; k < 4; k++) {
            float e = lrelu(fmaf(hv[k].x, a0, fmaf(hv[k].y, a1, ald)));
            float w = __expf(fminf(e, 80.f));
            w = (j + k < deg) ? w : 0.f;
            wsum += w;
            ax = fmaf(w, hv[k].x, ax);
            ay = fmaf(w, hv[k].y, ay);
        }
    }
    float inv = 1.f / (wsum + 1e-16f);
    out[n] = make_float2(ax * inv + bb0, ay * inv + bb1);
}

extern "C" void kernel_launch(void* const* d_in, const int* in_sizes, int n_in,
                              void* d_out, int out_size, void* d_ws, size_t ws_size,
                              hipStream_t stream) {
    const float* x     = (const float*)d_in[0];
    const int*   eidx  = (const int*)d_in[1];
    const float* W1    = (const float*)d_in[3];
    const float* asrc1 = (const float*)d_in[4];
    const float* adst1 = (const float*)d_in[5];
    const float* b1    = (const float*)d_in[6];
    const float* W2    = (const float*)d_in[7];
    const float* asrc2 = (const float*)d_in[8];
    const float* adst2 = (const float*)d_in[9];
    const float* b2    = (const float*)d_in[10];

    const int N = in_sizes[0] / 2;   // 100000 (< 2^17 for packing)
    const int E = in_sizes[1] / 2;   // 3200000
    const int* src = eidx;
    const int* dst = eidx + E;
    const int NB = (N + BK - 1) >> BK_BITS;   // 196

    // -------- workspace layout --------
    float* w = (float*)d_ws;
    float2* h2    = (float2*)w;                 // 2N floats
    float*  al2d  = w + 2 * (size_t)N;          // N
    int* ip       = (int*)(w + 3 * (size_t)N);
    int* row_deg  = ip;                         // N
    int* bcur     = ip + (size_t)N;             // NB
    int* pairs    = ip + (size_t)N + NB;        // NB*CAP  (start 4-aligned: (4N+NB)%4==0)
    int* csr_src  = pairs + (size_t)NB * CAP;   // NB*RSTRIDE (16B-aligned)

    const int B = 256;
    int gL = (N + B - 1) / B;
    int E4 = E >> 2;
    int gS = (E4 + 1023) / 1024;    // 4096 edges per block

    init_bcur<<<1, B, 0, stream>>>(bcur, NB);
    bucket_scatter<<<gS, B, 0, stream>>>(src, dst, bcur, pairs, E);
    csr_build<<<NB, 1024, 0, stream>>>(pairs, bcur, row_deg, csr_src, N);

    agg1_dstlane<<<gL, B, 0, stream>>>(row_deg, csr_src, (const float2*)x,
                                       W1, asrc1, adst1, b1, W2, asrc2, adst2,
                                       h2, al2d, N);
    agg2_dstlane<<<gL, B, 0, stream>>>(row_deg, csr_src, al2d, h2, asrc2, b2,
                                       (float2*)d_out, N);
}

// Round 12
// 184.830 us; speedup vs baseline: 2.6379x; 1.0316x over previous
//
#include <hip/hip_runtime.h>
#include <hip/hip_bf16.h>
#include <math.h>

#define NEG_SLOPE 0.2f
#define BK_BITS 9
#define BK (1 << BK_BITS)     // 512 dst per bucket -> NB = 196 buckets
#define SBITS 17              // bits for src id (N=100000 < 2^17)
#define SMASK ((1 << SBITS) - 1)
#define CAP 20480             // pairs capacity per bucket (mean 16327, +32 sigma)
#define RSTRIDE (CAP + 4 * BK)  // csr region per bucket (rows padded to x4)
#define PPT 17                // pairs cached in registers per csr_build thread

__device__ __forceinline__ float lrelu(float x) { return x > 0.f ? x : NEG_SLOPE * x; }

// ==================== init bucket cursors ====================
__global__ void init_bcur(int* __restrict__ bcur, int NB) {
    int i = threadIdx.x;
    if (i < NB) bcur[i] = i * CAP;
}

// ==================== LDS-staged bucketed scatter ====================
__global__ __launch_bounds__(256) void bucket_scatter(const int* __restrict__ src,
                                                      const int* __restrict__ dst,
                                                      int* __restrict__ bcur,
                                                      int* __restrict__ pairs, int E) {
    __shared__ int cnt[256], sc[256], off[256], cur[256], gbase[256];
    __shared__ int lpair[4096];
    __shared__ unsigned char lbkt[4096];
    int t = threadIdx.x;
    cnt[t] = 0;
    __syncthreads();

    int E4 = E >> 2;
    const int4* src4 = (const int4*)src;
    const int4* dst4 = (const int4*)dst;
    int base4 = blockIdx.x * 1024;
    int4 d4[4], s4[4];
    bool val[4];
#pragma unroll
    for (int k = 0; k < 4; k++) {
        int i4 = base4 + k * 256 + t;
        val[k] = (i4 < E4);
        if (val[k]) {
            d4[k] = dst4[i4];
            s4[k] = src4[i4];
            atomicAdd(&cnt[d4[k].x >> BK_BITS], 1);
            atomicAdd(&cnt[d4[k].y >> BK_BITS], 1);
            atomicAdd(&cnt[d4[k].z >> BK_BITS], 1);
            atomicAdd(&cnt[d4[k].w >> BK_BITS], 1);
        }
    }
    int dt = -1, st = 0;
    if (blockIdx.x == gridDim.x - 1) {
        int e = (E4 << 2) + t;
        if (e < E) { dt = dst[e]; st = src[e]; atomicAdd(&cnt[dt >> BK_BITS], 1); }
    }
    __syncthreads();

    sc[t] = cnt[t];
    __syncthreads();
    for (int o = 1; o < 256; o <<= 1) {
        int u = (t >= o) ? sc[t - o] : 0;
        __syncthreads();
        sc[t] += u;
        __syncthreads();
    }
    int excl = (t == 0) ? 0 : sc[t - 1];
    off[t] = excl;
    cur[t] = excl;
    if (cnt[t] > 0) gbase[t] = atomicAdd(&bcur[t], cnt[t]);
    __syncthreads();
    int total = sc[255];

#pragma unroll
    for (int k = 0; k < 4; k++) {
        if (val[k]) {
            int b, slot;
            b = d4[k].x >> BK_BITS; slot = atomicAdd(&cur[b], 1);
            lpair[slot] = ((d4[k].x & (BK - 1)) << SBITS) | s4[k].x; lbkt[slot] = (unsigned char)b;
            b = d4[k].y >> BK_BITS; slot = atomicAdd(&cur[b], 1);
            lpair[slot] = ((d4[k].y & (BK - 1)) << SBITS) | s4[k].y; lbkt[slot] = (unsigned char)b;
            b = d4[k].z >> BK_BITS; slot = atomicAdd(&cur[b], 1);
            lpair[slot] = ((d4[k].z & (BK - 1)) << SBITS) | s4[k].z; lbkt[slot] = (unsigned char)b;
            b = d4[k].w >> BK_BITS; slot = atomicAdd(&cur[b], 1);
            lpair[slot] = ((d4[k].w & (BK - 1)) << SBITS) | s4[k].w; lbkt[slot] = (unsigned char)b;
        }
    }
    if (dt >= 0) {
        int b = dt >> BK_BITS;
        int slot = atomicAdd(&cur[b], 1);
        lpair[slot] = ((dt & (BK - 1)) << SBITS) | st; lbkt[slot] = (unsigned char)b;
    }
    __syncthreads();

    for (int i = t; i < total; i += 256) {
        int b = lbkt[i];
        pairs[gbase[b] + (i - off[b])] = lpair[i];
    }
}

// ==================== CSR build: one block (1024 thr) per bucket ====================
// Pairs cached in registers (PPT each, static-indexed unrolled) so the pairs array
// is read from global exactly once. Rows padded to x4; pad slots = own dst index.
__global__ __launch_bounds__(1024) void csr_build(const int* __restrict__ pairs,
                                                  const int* __restrict__ bcur,
                                                  int* __restrict__ row_deg,
                                                  int* __restrict__ csr_src, int N) {
    int b = blockIdx.x;
    int t = threadIdx.x;
    int lo = b * CAP, hi = bcur[b];
    int dbase = b << BK_BITS;
    int ndst = min(BK, N - dbase);
    int base2 = b * RSTRIDE;
    __shared__ int cnt[BK];
    __shared__ int sc[256];
    __shared__ int cur[BK];
    if (t < BK) cnt[t] = 0;
    __syncthreads();

    int myp[PPT];
#pragma unroll
    for (int k = 0; k < PPT; k++) {
        int i = lo + t + k * 1024;
        int p = (i < hi) ? pairs[i] : -1;
        myp[k] = p;
        if (p >= 0) atomicAdd(&cnt[p >> SBITS], 1);
    }
    for (int i = lo + t + PPT * 1024; i < hi; i += 1024)   // ~never taken
        atomicAdd(&cnt[pairs[i] >> SBITS], 1);
    __syncthreads();

    int d0 = 0, d1 = 0, a0 = 0, a1 = 0;
    if (t < 256) {
        int i0 = 2 * t, i1 = 2 * t + 1;
        d0 = (i0 < ndst) ? cnt[i0] + 1 : 0;   // +1 self-loop
        d1 = (i1 < ndst) ? cnt[i1] + 1 : 0;
        a0 = (d0 + 3) & ~3;                   // padded size
        a1 = (d1 + 3) & ~3;
        sc[t] = a0 + a1;
    }
    __syncthreads();
    for (int o = 1; o < 256; o <<= 1) {
        int u = 0;
        if (t < 256 && t >= o) u = sc[t - o];
        __syncthreads();
        if (t < 256) sc[t] += u;
        __syncthreads();
    }
    if (t < 256) {
        int excl = (t == 0) ? 0 : sc[t - 1];
        int i0 = 2 * t, i1 = 2 * t + 1;
        if (i0 < ndst) {
            row_deg[dbase + i0] = (excl << 16) | d0;
            csr_src[base2 + excl] = dbase + i0;  // self-loop first
            for (int k = d0; k < a0; k++) csr_src[base2 + excl + k] = dbase + i0;  // pad
            cur[i0] = excl + 1;
        }
        excl += a0;
        if (i1 < ndst) {
            row_deg[dbase + i1] = (excl << 16) | d1;
            csr_src[base2 + excl] = dbase + i1;
            for (int k = d1; k < a1; k++) csr_src[base2 + excl + k] = dbase + i1;
            cur[i1] = excl + 1;
        }
    }
    __syncthreads();

#pragma unroll
    for (int k = 0; k < PPT; k++) {
        int p = myp[k];
        if (p >= 0) {
            int pos = atomicAdd(&cur[p >> SBITS], 1);
            csr_src[base2 + pos] = p & SMASK;
        }
    }
    for (int i = lo + t + PPT * 1024; i < hi; i += 1024) { // ~never taken
        int p = pairs[i];
        int pos = atomicAdd(&cur[p >> SBITS], 1);
        csr_src[base2 + pos] = p & SMASK;
    }
}

// ==================== fused layer1: 4 lanes per dst, register accumulate ==========
__global__ __launch_bounds__(256) void agg1_dstlane(
        const int* __restrict__ row_deg, const int* __restrict__ csr_src,
        const float2* __restrict__ x2,
        const float* __restrict__ W1, const float* __restrict__ asrc,
        const float* __restrict__ adst, const float* __restrict__ b1,
        const float* __restrict__ W2, const float* __restrict__ as2,
        const float* __restrict__ ad2,
        float2* __restrict__ h2, float* __restrict__ al2d, int N) {
    __shared__ float sW[64], sB[32], sW2[64], sP[4], sQ[4], sPd[4], sQd[4], sA2[4];
    int t = threadIdx.x;
    if (t < 64) { sW[t] = W1[t]; sW2[t] = W2[t]; }
    if (t < 32) sB[t] = b1[t];
    if (t < 2) { sA2[t] = as2[t]; sA2[2 + t] = ad2[t]; }
    if (t < 4) {
        float P = 0.f, Q = 0.f, Pd = 0.f, Qd = 0.f;
#pragma unroll
        for (int k = 0; k < 8; k++) {
            int c = t * 8 + k;
            float a = asrc[c], ad_ = adst[c];
            float w0 = W1[c], w1 = W1[32 + c];
            P += w0 * a; Q += w1 * a;
            Pd += w0 * ad_; Qd += w1 * ad_;
        }
        sP[t] = P; sQ[t] = Q; sPd[t] = Pd; sQd[t] = Qd;
    }
    __syncthreads();

    int tid = blockIdx.x * blockDim.x + t;
    int n = tid >> 2;
    int q = tid & 3;
    if (n >= N) return;
    int rd = row_deg[n];
    int row = (n >> BK_BITS) * RSTRIDE + (rd >> 16);
    int deg = rd & 0xFFFF;

    float2 xd = x2[n];
    float P[4], Q[4], ald[4];
#pragma unroll
    for (int h = 0; h < 4; h++) {
        P[h] = sP[h]; Q[h] = sQ[h];
        ald[h] = xd.x * sPd[h] + xd.y * sQd[h];
    }

    float Sw[4] = {0.f, 0.f, 0.f, 0.f};
    float S0[4] = {0.f, 0.f, 0.f, 0.f};
    float S1[4] = {0.f, 0.f, 0.f, 0.f};
    for (int j = q * 4; j < deg; j += 16) {
        int4 s4 = *(const int4*)(csr_src + row + j);   // 16B-aligned
        float2 xs[4];
        xs[0] = x2[s4.x]; xs[1] = x2[s4.y]; xs[2] = x2[s4.z]; xs[3] = x2[s4.w];
#pragma unroll
        for (int k = 0; k < 4; k++) {
            bool live = (j + k < deg);
#pragma unroll
            for (int h = 0; h < 4; h++) {
                float e = lrelu(fmaf(xs[k].x, P[h], fmaf(xs[k].y, Q[h], ald[h])));
                float w = __expf(fminf(e, 80.f));
                w = live ? w : 0.f;
                Sw[h] += w;
                S0[h] += w * xs[k].x;
                S1[h] += w * xs[k].y;
            }
        }
    }
    // combine the 4 lanes of this dst
#pragma unroll
    for (int o = 1; o <= 2; o <<= 1) {
#pragma unroll
        for (int h = 0; h < 4; h++) {
            Sw[h] += __shfl_xor(Sw[h], o);
            S0[h] += __shfl_xor(S0[h], o);
            S1[h] += __shfl_xor(S1[h], o);
        }
    }
    if (q != 0) return;

    float r[4];
#pragma unroll
    for (int h = 0; h < 4; h++) r[h] = 1.f / (Sw[h] + 1e-16f);
    float h20 = 0.f, h21 = 0.f;
#pragma unroll
    for (int c = 0; c < 32; c++) {
        int h = c >> 3;
        float outc = (sW[c] * S0[h] + sW[32 + c] * S1[h]) * r[h];
        float v2 = outc + sB[c];
        v2 = v2 > 0.f ? v2 : __expf(v2) - 1.f;  // elu
        h20 = fmaf(v2, sW2[2 * c], h20);
        h21 = fmaf(v2, sW2[2 * c + 1], h21);
    }
    h2[n] = make_float2(h20, h21);
    al2d[n] = h20 * sA2[2] + h21 * sA2[3];
}

// ==================== layer 2 aggregate: 4 lanes per dst ====================
__global__ __launch_bounds__(256) void agg2_dstlane(
        const int* __restrict__ row_deg, const int* __restrict__ csr_src,
        const float* __restrict__ al2d, const float2* __restrict__ h2,
        const float* __restrict__ as2, const float* __restrict__ b2,
        float2* __restrict__ out, int N) {
    int tid = blockIdx.x * blockDim.x + threadIdx.x;
    int n = tid >> 2;
    int q = tid & 3;
    if (n >= N) return;
    int rd = row_deg[n];
    int row = (n >> BK_BITS) * RSTRIDE + (rd >> 16);
    int deg = rd & 0xFFFF;
    float ald = al2d[n];
    float a0 = as2[0], a1 = as2[1];

    float wsum = 0.f, ax = 0.f, ay = 0.f;
    for (int j = q * 4; j < deg; j += 16) {
        int4 s4 = *(const int4*)(csr_src + row + j);
        float2 hv[4];
        hv[0] = h2[s4.x]; hv[1] = h2[s4.y]; hv[2] = h2[s4.z]; hv[3] = h2[s4.w];
#pragma unroll
        for (int k = 0; k < 4; k++) {
            float e = lrelu(fmaf(hv[k].x, a0, fmaf(hv[k].y, a1, ald)));
            float w = __expf(fminf(e, 80.f));
            w = (j + k < deg) ? w : 0.f;
            wsum += w;
            ax = fmaf(w, hv[k].x, ax);
            ay = fmaf(w, hv[k].y, ay);
        }
    }
#pragma unroll
    for (int o = 1; o <= 2; o <<= 1) {
        wsum += __shfl_xor(wsum, o);
        ax += __shfl_xor(ax, o);
        ay += __shfl_xor(ay, o);
    }
    if (q != 0) return;
    float inv = 1.f / (wsum + 1e-16f);
    out[n] = make_float2(ax * inv + b2[0], ay * inv + b2[1]);
}

extern "C" void kernel_launch(void* const* d_in, const int* in_sizes, int n_in,
                              void* d_out, int out_size, void* d_ws, size_t ws_size,
                              hipStream_t stream) {
    const float* x     = (const float*)d_in[0];
    const int*   eidx  = (const int*)d_in[1];
    const float* W1    = (const float*)d_in[3];
    const float* asrc1 = (const float*)d_in[4];
    const float* adst1 = (const float*)d_in[5];
    const float* b1    = (const float*)d_in[6];
    const float* W2    = (const float*)d_in[7];
    const float* asrc2 = (const float*)d_in[8];
    const float* adst2 = (const float*)d_in[9];
    const float* b2    = (const float*)d_in[10];

    const int N = in_sizes[0] / 2;   // 100000 (< 2^17 for packing)
    const int E = in_sizes[1] / 2;   // 3200000
    const int* src = eidx;
    const int* dst = eidx + E;
    const int NB = (N + BK - 1) >> BK_BITS;   // 196

    // -------- workspace layout --------
    float* w = (float*)d_ws;
    float2* h2    = (float2*)w;                 // 2N floats
    float*  al2d  = w + 2 * (size_t)N;          // N
    int* ip       = (int*)(w + 3 * (size_t)N);
    int* row_deg  = ip;                         // N
    int* bcur     = ip + (size_t)N;             // NB
    int* pairs    = ip + (size_t)N + NB;        // NB*CAP (4-aligned)
    int* csr_src  = pairs + (size_t)NB * CAP;   // NB*RSTRIDE (16B-aligned)

    const int B = 256;
    int E4 = E >> 2;
    int gS = (E4 + 1023) / 1024;        // 4096 edges per block
    int gL4 = (4 * N + B - 1) / B;      // 4 lanes per dst

    init_bcur<<<1, B, 0, stream>>>(bcur, NB);
    bucket_scatter<<<gS, B, 0, stream>>>(src, dst, bcur, pairs, E);
    csr_build<<<NB, 1024, 0, stream>>>(pairs, bcur, row_deg, csr_src, N);

    agg1_dstlane<<<gL4, B, 0, stream>>>(row_deg, csr_src, (const float2*)x,
                                        W1, asrc1, adst1, b1, W2, asrc2, adst2,
                                        h2, al2d, N);
    agg2_dstlane<<<gL4, B, 0, stream>>>(row_deg, csr_src, al2d, h2, asrc2, b2,
                                        (float2*)d_out, N);
}